// Round 1
// baseline (45.177 us; speedup 1.0000x reference)
//
#include <hip/hip_runtime.h>

#define TPB 256
#define FPB 256   // functions per block (1 per thread)

__global__ __launch_bounds__(TPB) void sat_main_kernel(
    const float* __restrict__ vp,        // variable_prediction [V]
    const int*   __restrict__ var_idx,   // graph_map row 0 [E]
    const float* __restrict__ ef,        // edge_feature [E]
    const float* __restrict__ gs,        // global_step [1]
    const float* __restrict__ epsp,      // eps [1]
    const float* __restrict__ maxcp,     // max_coeff [1]
    const int*   __restrict__ lsp,       // loss_sharpness [1]
    double*      __restrict__ partial,   // per-block partial sums
    int F, long long E)
{
    __shared__ int   s_idx[FPB * 3];
    __shared__ float s_ef [FPB * 3];

    const int tid = threadIdx.x;
    const long long blk = blockIdx.x;
    const long long ebase = blk * (long long)(FPB * 3);

    // Coalesced stage of this block's 768 edges into LDS.
    #pragma unroll
    for (int i = tid; i < FPB * 3; i += TPB) {
        long long g = ebase + i;
        if (g < E) {
            s_idx[i] = var_idx[g];
            s_ef [i] = ef[g];
        }
    }
    __syncthreads();

    const float coeff = fminf(powf(gs[0], 0.4f), maxcp[0]);
    const float eps   = epsp[0];
    const int   ls    = lsp[0];

    const long long f = blk * (long long)FPB + tid;
    float lg = 0.0f;
    if (f < (long long)F) {
        float nom = 0.0f, den = 0.0f;
        #pragma unroll
        for (int k = 0; k < 3; ++k) {
            const float e = s_ef[tid * 3 + k];
            const float v = vp[s_idx[tid * 3 + k]];
            const float ev = fmaf(e, v, (1.0f - e) * 0.5f);
            const float w  = __expf(coeff * ev);
            nom = fmaf(w, ev, nom);
            den += w;
        }
        const float cv = den / fmaxf(nom, eps);
        const float d  = cv - 1.0f;
        float p = 1.0f;
        for (int i = 0; i < ls; ++i) p *= d;   // integer power, matches (cv-1)**5
        const float cvv = 1.0f + p;
        lg = __logf(fmaxf(cvv, eps));
    }

    // Deterministic block reduction: wave64 shuffle -> LDS doubles -> lane 0.
    #pragma unroll
    for (int off = 32; off > 0; off >>= 1)
        lg += __shfl_down(lg, off, 64);

    __shared__ double s_part[TPB / 64];
    if ((tid & 63) == 0) s_part[tid >> 6] = (double)lg;
    __syncthreads();
    if (tid == 0) {
        double s = 0.0;
        #pragma unroll
        for (int w = 0; w < TPB / 64; ++w) s += s_part[w];
        partial[blk] = s;
    }
}

__global__ __launch_bounds__(256) void sat_reduce_kernel(
    const double* __restrict__ partial, int n, float* __restrict__ out, int F)
{
    const int tid = threadIdx.x;
    double s = 0.0;
    for (int i = tid; i < n; i += 256) s += partial[i];

    __shared__ double sm[256];
    sm[tid] = s;
    __syncthreads();
    #pragma unroll
    for (int off = 128; off > 0; off >>= 1) {
        if (tid < off) sm[tid] += sm[tid + off];
        __syncthreads();
    }
    if (tid == 0) out[0] = (float)(sm[0] / (double)F);
}

extern "C" void kernel_launch(void* const* d_in, const int* in_sizes, int n_in,
                              void* d_out, int out_size, void* d_ws, size_t ws_size,
                              hipStream_t stream) {
    // setup_inputs order:
    // 0 variable_prediction f32[V], 1 label f32[V], 2 graph_map i32[2E],
    // 3 batch_variable_map i32[V], 4 batch_function_map i32[F],
    // 5 edge_feature f32[E], 6 meta_data f32[1], 7 global_step f32[1],
    // 8 eps f32[1], 9 max_coeff f32[1], 10 loss_sharpness i32[1]
    const float* vp      = (const float*)d_in[0];
    const int*   gm      = (const int*)  d_in[2];   // row 0 = var_idx
    const float* ef      = (const float*)d_in[5];
    const float* gs      = (const float*)d_in[7];
    const float* epsp    = (const float*)d_in[8];
    const float* maxcp   = (const float*)d_in[9];
    const int*   lsp     = (const int*)  d_in[10];

    const long long E = (long long)in_sizes[5];
    const int F = in_sizes[4];

    double* partial = (double*)d_ws;
    const int nblocks = (F + FPB - 1) / FPB;

    sat_main_kernel<<<nblocks, TPB, 0, stream>>>(
        vp, gm, ef, gs, epsp, maxcp, lsp, partial, F, E);
    sat_reduce_kernel<<<1, 256, 0, stream>>>(partial, nblocks, (float*)d_out, F);
}

// Round 3
// 42.622 us; speedup vs baseline: 1.0600x; 1.0600x over previous
//
#include <hip/hip_runtime.h>

#define TPB 256
#define FPT 4                 // functions per thread
#define FPB (TPB * FPT)       // 1024 functions per block

typedef int   i32x4 __attribute__((ext_vector_type(4)));
typedef float f32x4 __attribute__((ext_vector_type(4)));

__global__ __launch_bounds__(TPB) void sat_main_kernel(
    const float* __restrict__ vp,        // variable_prediction [V]
    const int*   __restrict__ var_idx,   // graph_map row 0 [E]
    const float* __restrict__ ef,        // edge_feature [E]
    const float* __restrict__ gs,        // global_step [1]
    const float* __restrict__ epsp,      // eps [1]
    const float* __restrict__ maxcp,     // max_coeff [1]
    const int*   __restrict__ lsp,       // loss_sharpness [1]
    double*      __restrict__ partial,   // per-block partial sums
    int F)
{
    const int tid = threadIdx.x;
    const float coeff = fminf(powf(gs[0], 0.4f), maxcp[0]);
    const float eps   = epsp[0];
    const int   ls    = lsp[0];

    const long long fbase = (long long)blockIdx.x * FPB + (long long)tid * FPT;
    float lg = 0.0f;

    if (fbase + FPT <= (long long)F) {
        const long long eb = fbase * 3;   // 12 edges; 16B-aligned (48B/thread)

        const i32x4* ip = (const i32x4*)(var_idx + eb);
        i32x4 ia = __builtin_nontemporal_load(ip);
        i32x4 ib = __builtin_nontemporal_load(ip + 1);
        i32x4 ic = __builtin_nontemporal_load(ip + 2);

        const f32x4* epv = (const f32x4*)(ef + eb);
        f32x4 ea  = __builtin_nontemporal_load(epv);
        f32x4 eb4 = __builtin_nontemporal_load(epv + 1);
        f32x4 ec  = __builtin_nontemporal_load(epv + 2);

        int idx[12] = { ia.x, ia.y, ia.z, ia.w,
                        ib.x, ib.y, ib.z, ib.w,
                        ic.x, ic.y, ic.z, ic.w };
        float e[12] = { ea.x, ea.y, ea.z, ea.w,
                        eb4.x, eb4.y, eb4.z, eb4.w,
                        ec.x, ec.y, ec.z, ec.w };

        // Issue all 12 gathers before any consumption (MLP).
        float v[12];
        #pragma unroll
        for (int k = 0; k < 12; ++k) v[k] = vp[idx[k]];

        #pragma unroll
        for (int q = 0; q < FPT; ++q) {
            float nom = 0.0f, den = 0.0f;
            #pragma unroll
            for (int j = 0; j < 3; ++j) {
                const float e1 = e[q * 3 + j];
                const float ev = fmaf(e1, v[q * 3 + j], (1.0f - e1) * 0.5f);
                const float w  = __expf(coeff * ev);
                nom = fmaf(w, ev, nom);
                den += w;
            }
            const float cv = den / fmaxf(nom, eps);
            const float d  = cv - 1.0f;
            float p = 1.0f;
            for (int i = 0; i < ls; ++i) p *= d;
            lg += __logf(fmaxf(1.0f + p, eps));
        }
    } else {
        // Tail block: per-function guarded scalar path.
        for (int q = 0; q < FPT; ++q) {
            const long long f = fbase + q;
            if (f < (long long)F) {
                const long long eb = f * 3;
                float nom = 0.0f, den = 0.0f;
                #pragma unroll
                for (int j = 0; j < 3; ++j) {
                    const float e1 = ef[eb + j];
                    const float vv = vp[var_idx[eb + j]];
                    const float ev = fmaf(e1, vv, (1.0f - e1) * 0.5f);
                    const float w  = __expf(coeff * ev);
                    nom = fmaf(w, ev, nom);
                    den += w;
                }
                const float cv = den / fmaxf(nom, eps);
                const float d  = cv - 1.0f;
                float p = 1.0f;
                for (int i = 0; i < ls; ++i) p *= d;
                lg += __logf(fmaxf(1.0f + p, eps));
            }
        }
    }

    // Deterministic block reduction: wave64 shuffle -> LDS doubles -> lane 0.
    #pragma unroll
    for (int off = 32; off > 0; off >>= 1)
        lg += __shfl_down(lg, off, 64);

    __shared__ double s_part[TPB / 64];
    if ((tid & 63) == 0) s_part[tid >> 6] = (double)lg;
    __syncthreads();
    if (tid == 0) {
        double s = 0.0;
        #pragma unroll
        for (int w = 0; w < TPB / 64; ++w) s += s_part[w];
        partial[blockIdx.x] = s;
    }
}

__global__ __launch_bounds__(256) void sat_reduce_kernel(
    const double* __restrict__ partial, int n, float* __restrict__ out, int F)
{
    const int tid = threadIdx.x;
    double s = 0.0;
    for (int i = tid; i < n; i += 256) s += partial[i];

    __shared__ double sm[256];
    sm[tid] = s;
    __syncthreads();
    #pragma unroll
    for (int off = 128; off > 0; off >>= 1) {
        if (tid < off) sm[tid] += sm[tid + off];
        __syncthreads();
    }
    if (tid == 0) out[0] = (float)(sm[0] / (double)F);
}

extern "C" void kernel_launch(void* const* d_in, const int* in_sizes, int n_in,
                              void* d_out, int out_size, void* d_ws, size_t ws_size,
                              hipStream_t stream) {
    const float* vp      = (const float*)d_in[0];
    const int*   gm      = (const int*)  d_in[2];   // row 0 = var_idx
    const float* ef      = (const float*)d_in[5];
    const float* gs      = (const float*)d_in[7];
    const float* epsp    = (const float*)d_in[8];
    const float* maxcp   = (const float*)d_in[9];
    const int*   lsp     = (const int*)  d_in[10];

    const int F = in_sizes[4];

    double* partial = (double*)d_ws;
    const int nblocks = (F + FPB - 1) / FPB;   // 1954

    sat_main_kernel<<<nblocks, TPB, 0, stream>>>(
        vp, gm, ef, gs, epsp, maxcp, lsp, partial, F);
    sat_reduce_kernel<<<1, 256, 0, stream>>>(partial, nblocks, (float*)d_out, F);
}

// Round 4
// 42.260 us; speedup vs baseline: 1.0690x; 1.0086x over previous
//
#include <hip/hip_runtime.h>

#define TPB 256
#define FPT 4                 // functions per thread
#define FPB (TPB * FPT)       // 1024 functions per block

typedef int   i32x4 __attribute__((ext_vector_type(4)));
typedef float f32x4 __attribute__((ext_vector_type(4)));

__global__ __launch_bounds__(TPB) void sat_main_kernel(
    const float* __restrict__ vp,        // variable_prediction [V]
    const int*   __restrict__ var_idx,   // graph_map row 0 [E]
    const float* __restrict__ ef,        // edge_feature [E]
    const float* __restrict__ gs,        // global_step [1]
    const float* __restrict__ epsp,      // eps [1]
    const float* __restrict__ maxcp,     // max_coeff [1]
    const int*   __restrict__ lsp,       // loss_sharpness [1]
    double*      __restrict__ partial,   // per-block partial sums
    int F)
{
    const int tid = threadIdx.x;
    const float coeff = fminf(powf(gs[0], 0.4f), maxcp[0]);
    const float eps   = epsp[0];
    const int   ls    = lsp[0];

    const long long fbase = (long long)blockIdx.x * FPB + (long long)tid * FPT;
    float lg = 0.0f;

    if (fbase + FPT <= (long long)F) {
        const long long eb = fbase * 3;   // 12 edges; 16B-aligned (48B/thread)

        const i32x4* ip = (const i32x4*)(var_idx + eb);
        i32x4 ia = __builtin_nontemporal_load(ip);
        i32x4 ib = __builtin_nontemporal_load(ip + 1);
        i32x4 ic = __builtin_nontemporal_load(ip + 2);

        const f32x4* epv = (const f32x4*)(ef + eb);
        f32x4 ea  = __builtin_nontemporal_load(epv);
        f32x4 eb4 = __builtin_nontemporal_load(epv + 1);
        f32x4 ec  = __builtin_nontemporal_load(epv + 2);

        int idx[12] = { ia.x, ia.y, ia.z, ia.w,
                        ib.x, ib.y, ib.z, ib.w,
                        ic.x, ic.y, ic.z, ic.w };
        float e[12] = { ea.x, ea.y, ea.z, ea.w,
                        eb4.x, eb4.y, eb4.z, eb4.w,
                        ec.x, ec.y, ec.z, ec.w };

        // Issue all 12 gathers as agent-scope (L1-bypassing, sc-bit) loads.
        float v[12];
        #pragma unroll
        for (int k = 0; k < 12; ++k)
            v[k] = __hip_atomic_load(&vp[idx[k]], __ATOMIC_RELAXED,
                                     __HIP_MEMORY_SCOPE_AGENT);

        #pragma unroll
        for (int q = 0; q < FPT; ++q) {
            float nom = 0.0f, den = 0.0f;
            #pragma unroll
            for (int j = 0; j < 3; ++j) {
                const float e1 = e[q * 3 + j];
                const float ev = fmaf(e1, v[q * 3 + j], (1.0f - e1) * 0.5f);
                const float w  = __expf(coeff * ev);
                nom = fmaf(w, ev, nom);
                den += w;
            }
            const float cv = den / fmaxf(nom, eps);
            const float d  = cv - 1.0f;
            float p = 1.0f;
            for (int i = 0; i < ls; ++i) p *= d;
            lg += __logf(fmaxf(1.0f + p, eps));
        }
    } else {
        // Tail block: per-function guarded scalar path.
        for (int q = 0; q < FPT; ++q) {
            const long long f = fbase + q;
            if (f < (long long)F) {
                const long long eb2 = f * 3;
                float nom = 0.0f, den = 0.0f;
                #pragma unroll
                for (int j = 0; j < 3; ++j) {
                    const float e1 = ef[eb2 + j];
                    const float vv = vp[var_idx[eb2 + j]];
                    const float ev = fmaf(e1, vv, (1.0f - e1) * 0.5f);
                    const float w  = __expf(coeff * ev);
                    nom = fmaf(w, ev, nom);
                    den += w;
                }
                const float cv = den / fmaxf(nom, eps);
                const float d  = cv - 1.0f;
                float p = 1.0f;
                for (int i = 0; i < ls; ++i) p *= d;
                lg += __logf(fmaxf(1.0f + p, eps));
            }
        }
    }

    // Deterministic block reduction: wave64 shuffle -> LDS doubles -> lane 0.
    #pragma unroll
    for (int off = 32; off > 0; off >>= 1)
        lg += __shfl_down(lg, off, 64);

    __shared__ double s_part[TPB / 64];
    if ((tid & 63) == 0) s_part[tid >> 6] = (double)lg;
    __syncthreads();
    if (tid == 0) {
        double s = 0.0;
        #pragma unroll
        for (int w = 0; w < TPB / 64; ++w) s += s_part[w];
        partial[blockIdx.x] = s;
    }
}

__global__ __launch_bounds__(256) void sat_reduce_kernel(
    const double* __restrict__ partial, int n, float* __restrict__ out, int F)
{
    const int tid = threadIdx.x;
    double s = 0.0;
    for (int i = tid; i < n; i += 256) s += partial[i];

    __shared__ double sm[256];
    sm[tid] = s;
    __syncthreads();
    #pragma unroll
    for (int off = 128; off > 0; off >>= 1) {
        if (tid < off) sm[tid] += sm[tid + off];
        __syncthreads();
    }
    if (tid == 0) out[0] = (float)(sm[0] / (double)F);
}

extern "C" void kernel_launch(void* const* d_in, const int* in_sizes, int n_in,
                              void* d_out, int out_size, void* d_ws, size_t ws_size,
                              hipStream_t stream) {
    const float* vp      = (const float*)d_in[0];
    const int*   gm      = (const int*)  d_in[2];   // row 0 = var_idx
    const float* ef      = (const float*)d_in[5];
    const float* gs      = (const float*)d_in[7];
    const float* epsp    = (const float*)d_in[8];
    const float* maxcp   = (const float*)d_in[9];
    const int*   lsp     = (const int*)  d_in[10];

    const int F = in_sizes[4];

    double* partial = (double*)d_ws;
    const int nblocks = (F + FPB - 1) / FPB;   // 1954

    sat_main_kernel<<<nblocks, TPB, 0, stream>>>(
        vp, gm, ef, gs, epsp, maxcp, lsp, partial, F);
    sat_reduce_kernel<<<1, 256, 0, stream>>>(partial, nblocks, (float*)d_out, F);
}